// Round 6
// baseline (323.211 us; speedup 1.0000x reference)
//
#include <hip/hip_runtime.h>
#include <hip/hip_bf16.h>

#define M_TOT 16384
#define D_DIM 256
#define C_TOT 8192
#define NCH 4
#define CCH (C_TOT / NCH)     // 2048
#define QOFF (M_TOT * D_DIM)
#define NPART 8               // 4 C-chunks x 2 wave-columns

typedef _Float16 f16;
typedef __attribute__((ext_vector_type(8))) _Float16 f16x8;
typedef __attribute__((ext_vector_type(4))) float f32x4;

// ---- workspace layout (float units) ----
#define WS_X2 0
#define WS_E2 (M_TOT)
#define WS_BV (M_TOT + C_TOT)
#define WS_BI (WS_BV + NPART * M_TOT)
#define WS_SPL (WS_BI + NPART * M_TOT)
// half-unit offsets within the split region
#define XH_OFF ((size_t)0)
#define XL_OFF ((size_t)M_TOT * D_DIM)
#define EH_OFF ((size_t)2 * M_TOT * D_DIM)
#define EL_OFF ((size_t)2 * M_TOT * D_DIM + (size_t)C_TOT * D_DIM)
#define SPL_HALFS ((size_t)2 * M_TOT * D_DIM + (size_t)2 * C_TOT * D_DIM)
#define WS_NEED ((size_t)WS_SPL * 4 + SPL_HALFS * 2)

__device__ __forceinline__ void gll16(const void* g, void* l) {
    __builtin_amdgcn_global_load_lds((const __attribute__((address_space(1))) void*)g,
                                     (__attribute__((address_space(3))) void*)l, 16, 0, 0);
}

// ---------- split: fp16 (hi,lo) decomposition + row sums of squares ----------
__global__ void split_kernel(const float* __restrict__ x, const float* __restrict__ e,
                             f16* __restrict__ sp, float* __restrict__ x2, float* __restrict__ e2)
{
    int row  = blockIdx.x * 4 + (threadIdx.x >> 6);
    int lane = threadIdx.x & 63;
    bool isx = row < M_TOT;
    int r = isx ? row : row - M_TOT;
    const float* src = (isx ? x : e) + (size_t)r * D_DIM;
    float4 v = *(const float4*)(src + lane * 4);
    float s = v.x * v.x + v.y * v.y + v.z * v.z + v.w * v.w;  // ORIGINAL scale
    #pragma unroll
    for (int off = 32; off >= 1; off >>= 1) s += __shfl_xor(s, off, 64);
    float sc = isx ? 256.0f : 16384.0f;
    float a[4] = {v.x * sc, v.y * sc, v.z * sc, v.w * sc};
    union { f16 h[4]; ushort4 u; } hh, ll;
    #pragma unroll
    for (int i = 0; i < 4; ++i) {
        f16 h = (f16)a[i];
        hh.h[i] = h;
        ll.h[i] = (f16)(a[i] - (float)h);
    }
    size_t base = (size_t)r * D_DIM + lane * 4;
    f16* ph = sp + (isx ? XH_OFF : EH_OFF) + base;
    f16* pl = sp + (isx ? XL_OFF : EL_OFF) + base;
    *(ushort4*)ph = hh.u;
    *(ushort4*)pl = ll.u;
    if (lane == 0) { if (isx) x2[r] = s; else e2[r] = s; }
}

// ---------- MFMA distance + fused argmin ----------
// 256x256 block tile, 8 waves (4x2: 64x128 per wave), BK=32, 3-term fp16 split
// GEMM S = xh*eh + xh*el + xl*eh; d = fma(S, -2^-21, x2) + e2.
// 3-phase counted-vmcnt schedule (T3+T4): stage order [xh,eh,el,xl];
// phase waits vmcnt(4)/vmcnt(10)/vmcnt(8) — never drains to 0 in the loop.
__global__ __launch_bounds__(512, 2) void mdist_kernel(
    const f16* __restrict__ sp, const float* __restrict__ x2, const float* __restrict__ e2,
    float* __restrict__ bestv, int* __restrict__ besti)
{
    __shared__ __align__(16) f16 lds[65536];  // 128 KB

    const int t  = threadIdx.x;          // 0..511
    const int l  = t & 63;
    const int wv = t >> 6;               // 0..7
    const int wr = wv >> 1, wc = wv & 1; // 4x2 wave grid: rows wr*64, cols wc*128
    const int mt = (int)blockIdx.x >> 2;
    const int ch = (int)blockIdx.x & 3;
    const int m0 = mt * 256, c0 = ch * CCH;

    const int q  = l >> 4;   // fragment k-block / row-quad (0..3)
    const int fr = l & 15;

    // staging: unit = (tensor tn, kb, rowblk rb); wvh selects kb phase, rb=wv&3
    const int wvh = wv >> 2, rb = wv & 3;
    const f16* gxh = sp + XH_OFF + (size_t)(m0 + rb * 64 + l) * D_DIM;
    const f16* gxl = sp + XL_OFF + (size_t)(m0 + rb * 64 + l) * D_DIM;
    const f16* geh = sp + EH_OFF + (size_t)(c0 + rb * 64 + l) * D_DIM;
    const f16* gel = sp + EL_OFF + (size_t)(c0 + rb * 64 + l) * D_DIM;
    char* lbase = (char*)&lds[0] + rb * 1024 + l * 16;

#define KB(it) ((2 * (it) + wvh) & 3)
    // issue order matters for the counted vmcnt thresholds: [xh, eh, el, xl]
    auto STAGE = [&](int buf, int ktv, int ctv) {
        const size_t ko = (size_t)ktv * 32;
        const size_t co = (size_t)ctv * 256 * D_DIM + ko;
        char* lb = lbase + buf * 65536;
        gll16(gxh + ko + KB(0) * 8, lb + 0 * 16384 + KB(0) * 4096);
        gll16(gxh + ko + KB(1) * 8, lb + 0 * 16384 + KB(1) * 4096);
        gll16(geh + co + KB(4) * 8, lb + 2 * 16384 + KB(4) * 4096);
        gll16(geh + co + KB(5) * 8, lb + 2 * 16384 + KB(5) * 4096);
        gll16(gel + co + KB(6) * 8, lb + 3 * 16384 + KB(6) * 4096);
        gll16(gel + co + KB(7) * 8, lb + 3 * 16384 + KB(7) * 4096);
        gll16(gxl + ko + KB(2) * 8, lb + 1 * 16384 + KB(2) * 4096);
        gll16(gxl + ko + KB(3) * 8, lb + 1 * 16384 + KB(3) * 4096);
    };

    float bst[16]; int bix[16];
    #pragma unroll
    for (int i = 0; i < 16; ++i) { bst[i] = 3.4e38f; bix[i] = 0; }

    STAGE(0, 0, 0);

    for (int ct = 0; ct < 8; ++ct) {
        const int cb = c0 + ct * 256;
        f32x4 acc[4][8];
        #pragma unroll
        for (int m = 0; m < 4; ++m)
            #pragma unroll
            for (int n = 0; n < 8; ++n)
                #pragma unroll
                for (int k = 0; k < 4; ++k) acc[m][n][k] = 0.f;

        #pragma unroll 1
        for (int kt = 0; kt < 8; ++kt) {
            const int cur = kt & 1;
            const f16* L = &lds[0] + cur * 32768;  // halfs

            // ===== phase 1: xh . eh =====
            __builtin_amdgcn_sched_barrier(0);
            asm volatile("s_waitcnt vmcnt(4)" ::: "memory");  // own xh,eh of cur done
            __syncthreads();                                   // => ALL waves' xh,eh done
            __builtin_amdgcn_sched_barrier(0);

            // prefetch next tile into cur^1 (all waves finished reading it above)
            if (kt < 7) STAGE(cur ^ 1, kt + 1, ct);
            else        STAGE(cur ^ 1, 0, (ct + 1) & 7);  // uniform count; last is waste

            f16x8 ah[4], bh[8];
            #pragma unroll
            for (int m = 0; m < 4; ++m)
                ah[m] = *(const f16x8*)(L + (size_t)(q * 256 + wr * 64 + m * 16 + fr) * 8);
            #pragma unroll
            for (int n = 0; n < 8; ++n)
                bh[n] = *(const f16x8*)(L + 16384 + (size_t)(q * 256 + wc * 128 + n * 16 + fr) * 8);
            __builtin_amdgcn_s_setprio(1);
            #pragma unroll
            for (int m = 0; m < 4; ++m)
                #pragma unroll
                for (int n = 0; n < 8; ++n)
                    acc[m][n] = __builtin_amdgcn_mfma_f32_16x16x32_f16(ah[m], bh[n], acc[m][n], 0, 0, 0);
            __builtin_amdgcn_s_setprio(0);

            // ===== phase 2: xh . el =====
            __builtin_amdgcn_sched_barrier(0);
            asm volatile("s_waitcnt vmcnt(10)" ::: "memory");  // old el done (8 new in flight)
            __syncthreads();
            __builtin_amdgcn_sched_barrier(0);

            f16x8 bl[8];
            #pragma unroll
            for (int n = 0; n < 8; ++n)
                bl[n] = *(const f16x8*)(L + 24576 + (size_t)(q * 256 + wc * 128 + n * 16 + fr) * 8);
            __builtin_amdgcn_s_setprio(1);
            #pragma unroll
            for (int m = 0; m < 4; ++m)
                #pragma unroll
                for (int n = 0; n < 8; ++n)
                    acc[m][n] = __builtin_amdgcn_mfma_f32_16x16x32_f16(ah[m], bl[n], acc[m][n], 0, 0, 0);
            __builtin_amdgcn_s_setprio(0);

            // ===== phase 3: xl . eh =====
            __builtin_amdgcn_sched_barrier(0);
            asm volatile("s_waitcnt vmcnt(8)" ::: "memory");   // old xl done
            __syncthreads();
            __builtin_amdgcn_sched_barrier(0);

            f16x8 al[4];
            #pragma unroll
            for (int m = 0; m < 4; ++m)
                al[m] = *(const f16x8*)(L + 8192 + (size_t)(q * 256 + wr * 64 + m * 16 + fr) * 8);
            __builtin_amdgcn_s_setprio(1);
            #pragma unroll
            for (int m = 0; m < 4; ++m)
                #pragma unroll
                for (int n = 0; n < 8; ++n)
                    acc[m][n] = __builtin_amdgcn_mfma_f32_16x16x32_f16(al[m], bh[n], acc[m][n], 0, 0, 0);
            __builtin_amdgcn_s_setprio(0);
        }

        // epilogue: fold into running argmin (cols ascend in (ct, n) => '<' keeps first)
        float e2v[8];
        #pragma unroll
        for (int n = 0; n < 8; ++n) e2v[n] = e2[cb + wc * 128 + n * 16 + fr];
        #pragma unroll
        for (int m = 0; m < 4; ++m) {
            f32x4 x2v = *(const f32x4*)(x2 + m0 + wr * 64 + m * 16 + q * 4);
            #pragma unroll
            for (int j = 0; j < 4; ++j) {
                const int bi = m * 4 + j;
                #pragma unroll
                for (int n = 0; n < 8; ++n) {
                    float d = fmaf(acc[m][n][j], -0x1p-21f, x2v[j]) + e2v[n];
                    int c = cb + wc * 128 + n * 16 + fr;
                    if (d < bst[bi]) { bst[bi] = d; bix[bi] = c; }
                }
            }
        }
    }

    // merge the 16 lanes sharing each output row; ties -> lower col
    #pragma unroll
    for (int i = 0; i < 16; ++i) {
        float v = bst[i]; int idx = bix[i];
        #pragma unroll
        for (int off = 8; off >= 1; off >>= 1) {
            float ov = __shfl_xor(v, off, 64);
            int   oi = __shfl_xor(idx, off, 64);
            if (ov < v || (ov == v && oi < idx)) { v = ov; idx = oi; }
        }
        if (fr == 0) {
            int row = m0 + wr * 64 + (i >> 2) * 16 + q * 4 + (i & 3);
            int p = ch * 2 + wc;
            bestv[p * M_TOT + row] = v;
            besti[p * M_TOT + row] = idx;
        }
    }
}

// ---------- finalize: merge partials (explicit index tie-break), gather ----------
__global__ void finalize_kernel(const float* __restrict__ e,
                                const float* __restrict__ bestv,
                                const int* __restrict__ besti,
                                float* __restrict__ out, int npart)
{
    int m    = blockIdx.x * 4 + (threadIdx.x >> 6);
    int lane = threadIdx.x & 63;
    float bv = bestv[m]; int bi = besti[m];
    for (int h = 1; h < npart; ++h) {
        float v = bestv[h * M_TOT + m];
        int   i2 = besti[h * M_TOT + m];
        if (v < bv || (v == bv && i2 < bi)) { bv = v; bi = i2; }
    }
    if (lane == 0) out[QOFF + m] = (float)bi;
    float4 v = *(const float4*)(e + (size_t)bi * D_DIM + lane * 4);
    *(float4*)(out + (size_t)m * D_DIM + lane * 4) = v;
}

// ================= fallback fp32 path (only if ws too small) =================
#define BMm 128
#define BNn 128
#define BKk 16
#define BSW 144
#define NKT (D_DIM / BKk)
#define NCT (CCH / BNn)

__device__ __forceinline__ int pcol(int c) { return c + ((c >> 5) << 2); }

__global__ void sq_kernel(const float* __restrict__ x, const float* __restrict__ e,
                          float* __restrict__ x2, float* __restrict__ e2) {
    int row  = blockIdx.x * 4 + (threadIdx.x >> 6);
    int lane = threadIdx.x & 63;
    const float* src = (row < M_TOT) ? (x + (size_t)row * D_DIM)
                                     : (e + (size_t)(row - M_TOT) * D_DIM);
    float4 v = *(const float4*)(src + lane * 4);
    float s = v.x * v.x + v.y * v.y + v.z * v.z + v.w * v.w;
    #pragma unroll
    for (int off = 32; off >= 1; off >>= 1) s += __shfl_xor(s, off, 64);
    if (lane == 0) { if (row < M_TOT) x2[row] = s; else e2[row - M_TOT] = s; }
}

__global__ __launch_bounds__(256, 1) void dist_kernel(
    const float* __restrict__ x, const float* __restrict__ e,
    const float* __restrict__ x2, const float* __restrict__ e2,
    float* __restrict__ bestv, int* __restrict__ besti)
{
    __shared__ __align__(16) float As[2][BKk][BMm];
    __shared__ __align__(16) float Bs[2][BKk][BSW];
    const int t  = threadIdx.x;
    const int ty = t >> 4, tx = t & 15;
    const int mt = (int)blockIdx.x >> 2;
    const int ch = (int)blockIdx.x & 3;
    const int m0 = mt * BMm, c0 = ch * CCH;
    float x2r[8];
    #pragma unroll
    for (int i = 0; i < 8; ++i) x2r[i] = x2[m0 + ty * 8 + i];
    float best[8]; int bidx[8];
    #pragma unroll
    for (int i = 0; i < 8; ++i) { best[i] = 3.4e38f; bidx[i] = 0; }
    const int r0  = t >> 2;
    const int cq0 = (t & 3) << 2;
    for (int ct = 0; ct < NCT; ++ct) {
        const int cb = c0 + ct * BNn;
        float acc[8][8];
        #pragma unroll
        for (int i = 0; i < 8; ++i)
            #pragma unroll
            for (int j = 0; j < 8; ++j) acc[i][j] = 0.f;
        #pragma unroll
        for (int it = 0; it < 2; ++it) {
            int r = r0 + it * 64;
            float4 va = *(const float4*)(x + (size_t)(m0 + r) * D_DIM + cq0);
            float4 vb = *(const float4*)(e + (size_t)(cb + r) * D_DIM + cq0);
            As[0][cq0 + 0][r] = va.x; As[0][cq0 + 1][r] = va.y;
            As[0][cq0 + 2][r] = va.z; As[0][cq0 + 3][r] = va.w;
            int pr = pcol(r);
            Bs[0][cq0 + 0][pr] = vb.x; Bs[0][cq0 + 1][pr] = vb.y;
            Bs[0][cq0 + 2][pr] = vb.z; Bs[0][cq0 + 3][pr] = vb.w;
        }
        __syncthreads();
        #pragma unroll 1
        for (int kt = 0; kt < NKT; ++kt) {
            const int cur = kt & 1;
            float4 pa[2], pb[2];
            if (kt + 1 < NKT) {
                const int k0 = (kt + 1) * BKk;
                #pragma unroll
                for (int it = 0; it < 2; ++it) {
                    int r = r0 + it * 64;
                    pa[it] = *(const float4*)(x + (size_t)(m0 + r) * D_DIM + k0 + cq0);
                    pb[it] = *(const float4*)(e + (size_t)(cb + r) * D_DIM + k0 + cq0);
                }
            }
            #pragma unroll
            for (int k = 0; k < BKk; ++k) {
                float a[8], b[8];
                *(float4*)&a[0] = *(const float4*)&As[cur][k][ty * 8];
                *(float4*)&a[4] = *(const float4*)&As[cur][k][ty * 8 + 4];
                const int pb0 = pcol(tx * 8);
                *(float4*)&b[0] = *(const float4*)&Bs[cur][k][pb0];
                *(float4*)&b[4] = *(const float4*)&Bs[cur][k][pb0 + 4];
                #pragma unroll
                for (int i = 0; i < 8; ++i)
                    #pragma unroll
                    for (int j = 0; j < 8; ++j)
                        acc[i][j] = fmaf(a[i], b[j], acc[i][j]);
            }
            __syncthreads();
            if (kt + 1 < NKT) {
                const int nb = cur ^ 1;
                #pragma unroll
                for (int it = 0; it < 2; ++it) {
                    int r = r0 + it * 64;
                    As[nb][cq0 + 0][r] = pa[it].x; As[nb][cq0 + 1][r] = pa[it].y;
                    As[nb][cq0 + 2][r] = pa[it].z; As[nb][cq0 + 3][r] = pa[it].w;
                    int pr = pcol(r);
                    Bs[nb][cq0 + 0][pr] = pb[it].x; Bs[nb][cq0 + 1][pr] = pb[it].y;
                    Bs[nb][cq0 + 2][pr] = pb[it].z; Bs[nb][cq0 + 3][pr] = pb[it].w;
                }
                __syncthreads();
            }
        }
        float e2v[8];
        #pragma unroll
        for (int j = 0; j < 8; ++j) e2v[j] = e2[cb + tx * 8 + j];
        #pragma unroll
        for (int i = 0; i < 8; ++i) {
            #pragma unroll
            for (int j = 0; j < 8; ++j) {
                float d = (x2r[i] - 2.0f * acc[i][j]) + e2v[j];
                int c = cb + tx * 8 + j;
                if (d < best[i]) { best[i] = d; bidx[i] = c; }
            }
        }
    }
    #pragma unroll
    for (int i = 0; i < 8; ++i) {
        float v = best[i]; int idx = bidx[i];
        #pragma unroll
        for (int off = 8; off >= 1; off >>= 1) {
            float ov = __shfl_xor(v, off, 64);
            int   oi = __shfl_xor(idx, off, 64);
            if (ov < v || (ov == v && oi < idx)) { v = ov; idx = oi; }
        }
        if (tx == 0) {
            int row = m0 + ty * 8 + i;
            bestv[ch * M_TOT + row] = v;
            besti[ch * M_TOT + row] = idx;
        }
    }
}

extern "C" void kernel_launch(void* const* d_in, const int* in_sizes, int n_in,
                              void* d_out, int out_size, void* d_ws, size_t ws_size,
                              hipStream_t stream) {
    const float* x = (const float*)d_in[0];   // [16384, 256]
    const float* e = (const float*)d_in[1];   // [8192, 256]
    float* out = (float*)d_out;

    float* wsf   = (float*)d_ws;
    float* x2    = wsf + WS_X2;
    float* e2    = wsf + WS_E2;
    float* bestv = wsf + WS_BV;
    int*   besti = (int*)(wsf + WS_BI);

    if (ws_size >= WS_NEED) {
        f16* sp = (f16*)(wsf + WS_SPL);
        split_kernel<<<(M_TOT + C_TOT) / 4, 256, 0, stream>>>(x, e, sp, x2, e2);
        mdist_kernel<<<(M_TOT / 256) * NCH, 512, 0, stream>>>(sp, x2, e2, bestv, besti);
        finalize_kernel<<<M_TOT / 4, 256, 0, stream>>>(e, bestv, besti, out, NPART);
    } else {
        sq_kernel<<<(M_TOT + C_TOT) / 4, 256, 0, stream>>>(x, e, x2, e2);
        dist_kernel<<<(M_TOT / BMm) * NCH, 256, 0, stream>>>(x, e, x2, e2, bestv, besti);
        finalize_kernel<<<M_TOT / 4, 256, 0, stream>>>(e, bestv, besti, out, NCH);
    }
}

// Round 7
// 260.026 us; speedup vs baseline: 1.2430x; 1.2430x over previous
//
#include <hip/hip_runtime.h>
#include <hip/hip_bf16.h>

#define M_TOT 16384
#define D_DIM 256
#define C_TOT 8192
#define NCH 4
#define CCH (C_TOT / NCH)     // 2048
#define QOFF (M_TOT * D_DIM)
#define NPART 8               // 4 C-chunks x 2 wave-columns

typedef _Float16 f16;
typedef __attribute__((ext_vector_type(8))) _Float16 f16x8;
typedef __attribute__((ext_vector_type(4))) float f32x4;

// ---- workspace layout (float units) ----
#define WS_X2 0
#define WS_E2 (M_TOT)
#define WS_BV (M_TOT + C_TOT)
#define WS_BI (WS_BV + NPART * M_TOT)
#define WS_SPL (WS_BI + NPART * M_TOT)
// half-unit offsets within the split region
#define XH_OFF ((size_t)0)
#define XL_OFF ((size_t)M_TOT * D_DIM)
#define EH_OFF ((size_t)2 * M_TOT * D_DIM)
#define EL_OFF ((size_t)2 * M_TOT * D_DIM + (size_t)C_TOT * D_DIM)
#define SPL_HALFS ((size_t)2 * M_TOT * D_DIM + (size_t)2 * C_TOT * D_DIM)
#define WS_NEED ((size_t)WS_SPL * 4 + SPL_HALFS * 2)

__device__ __forceinline__ void gll16(const void* g, void* l) {
    __builtin_amdgcn_global_load_lds((const __attribute__((address_space(1))) void*)g,
                                     (__attribute__((address_space(3))) void*)l, 16, 0, 0);
}

// ---------- split: fp16 (hi,lo) decomposition + row sums of squares ----------
__global__ void split_kernel(const float* __restrict__ x, const float* __restrict__ e,
                             f16* __restrict__ sp, float* __restrict__ x2, float* __restrict__ e2)
{
    int row  = blockIdx.x * 4 + (threadIdx.x >> 6);
    int lane = threadIdx.x & 63;
    bool isx = row < M_TOT;
    int r = isx ? row : row - M_TOT;
    const float* src = (isx ? x : e) + (size_t)r * D_DIM;
    float4 v = *(const float4*)(src + lane * 4);
    float s = v.x * v.x + v.y * v.y + v.z * v.z + v.w * v.w;  // ORIGINAL scale
    #pragma unroll
    for (int off = 32; off >= 1; off >>= 1) s += __shfl_xor(s, off, 64);
    float sc = isx ? 256.0f : 16384.0f;
    float a[4] = {v.x * sc, v.y * sc, v.z * sc, v.w * sc};
    union { f16 h[4]; ushort4 u; } hh, ll;
    #pragma unroll
    for (int i = 0; i < 4; ++i) {
        f16 h = (f16)a[i];
        hh.h[i] = h;
        ll.h[i] = (f16)(a[i] - (float)h);
    }
    size_t base = (size_t)r * D_DIM + lane * 4;
    f16* ph = sp + (isx ? XH_OFF : EH_OFF) + base;
    f16* pl = sp + (isx ? XL_OFF : EL_OFF) + base;
    *(ushort4*)ph = hh.u;
    *(ushort4*)pl = ll.u;
    if (lane == 0) { if (isx) x2[r] = s; else e2[r] = s; }
}

// ---------- MFMA distance + fused argmin ----------
// 256x256 block tile, 8 waves (4x2: 64x128 per wave), BK=32, 3-term fp16 split
// GEMM S = xh*eh + xh*el + xl*eh; d = fma(S, -2^-21, x2) + e2.
// R5 skeleton (single vmcnt(0)+barrier per kt). kt body is n-outer to cut
// operand liveness 48 -> ~20 VGPRs (R5 spilled: WRITE_SIZE 85MB of scratch).
__global__ __launch_bounds__(512, 2) void mdist_kernel(
    const f16* __restrict__ sp, const float* __restrict__ x2, const float* __restrict__ e2,
    float* __restrict__ bestv, int* __restrict__ besti)
{
    __shared__ __align__(16) f16 lds[65536];  // 128 KB

    const int t  = threadIdx.x;          // 0..511
    const int l  = t & 63;
    const int wv = t >> 6;               // 0..7
    const int wr = wv >> 1, wc = wv & 1; // 4x2 wave grid: rows wr*64, cols wc*128
    const int mt = (int)blockIdx.x >> 2;
    const int ch = (int)blockIdx.x & 3;
    const int m0 = mt * 256, c0 = ch * CCH;

    const int q  = l >> 4;   // fragment k-block / row-quad (0..3)
    const int fr = l & 15;

    // staging: unit = (tensor tn, kb, rowblk rb); wvh selects kb phase, rb=wv&3
    const int wvh = wv >> 2, rb = wv & 3;
    const f16* gxh = sp + XH_OFF + (size_t)(m0 + rb * 64 + l) * D_DIM;
    const f16* gxl = sp + XL_OFF + (size_t)(m0 + rb * 64 + l) * D_DIM;
    const f16* geh = sp + EH_OFF + (size_t)(c0 + rb * 64 + l) * D_DIM;
    const f16* gel = sp + EL_OFF + (size_t)(c0 + rb * 64 + l) * D_DIM;
    char* lbase = (char*)&lds[0] + rb * 1024 + l * 16;

#define KB(it) ((2 * (it) + wvh) & 3)
    auto STAGE = [&](int buf, int ktv, int ctv) {
        const size_t ko = (size_t)ktv * 32;
        const size_t co = (size_t)ctv * 256 * D_DIM + ko;
        char* lb = lbase + buf * 65536;
        gll16(gxh + ko + KB(0) * 8, lb + 0 * 16384 + KB(0) * 4096);
        gll16(gxh + ko + KB(1) * 8, lb + 0 * 16384 + KB(1) * 4096);
        gll16(gxl + ko + KB(2) * 8, lb + 1 * 16384 + KB(2) * 4096);
        gll16(gxl + ko + KB(3) * 8, lb + 1 * 16384 + KB(3) * 4096);
        gll16(geh + co + KB(4) * 8, lb + 2 * 16384 + KB(4) * 4096);
        gll16(geh + co + KB(5) * 8, lb + 2 * 16384 + KB(5) * 4096);
        gll16(gel + co + KB(6) * 8, lb + 3 * 16384 + KB(6) * 4096);
        gll16(gel + co + KB(7) * 8, lb + 3 * 16384 + KB(7) * 4096);
    };

    float bst[16]; int bix[16];
    #pragma unroll
    for (int i = 0; i < 16; ++i) { bst[i] = 3.4e38f; bix[i] = 0; }

    STAGE(0, 0, 0);

    for (int ct = 0; ct < 8; ++ct) {
        const int cb = c0 + ct * 256;
        f32x4 acc[4][8];
        #pragma unroll
        for (int m = 0; m < 4; ++m)
            #pragma unroll
            for (int n = 0; n < 8; ++n)
                #pragma unroll
                for (int k = 0; k < 4; ++k) acc[m][n][k] = 0.f;

        #pragma unroll 1
        for (int kt = 0; kt < 8; ++kt) {
            const int cur = kt & 1;
            // drain LDS-DMA that staged lds[cur] (race-proven R3/R5 skeleton)
            asm volatile("s_waitcnt vmcnt(0)" ::: "memory");
            __syncthreads();
            __builtin_amdgcn_sched_barrier(0);

            if (kt < 7)       STAGE(cur ^ 1, kt + 1, ct);
            else if (ct < 7)  STAGE(cur ^ 1, 0, ct + 1);

            const f16* L = &lds[0] + cur * 32768;  // halfs

            // A fragments for this kt: 8 x f16x8 = 16 VGPR
            f16x8 ah[4], al[4];
            #pragma unroll
            for (int m = 0; m < 4; ++m) {
                int aoff = (q * 256 + wr * 64 + m * 16 + fr) * 8;
                ah[m] = *(const f16x8*)(L + aoff);
                al[m] = *(const f16x8*)(L + 8192 + aoff);
            }
            // n-outer: only bh_n, bl_n live at a time (4 VGPR)
            #pragma unroll
            for (int n = 0; n < 8; ++n) {
                int boff = (q * 256 + wc * 128 + n * 16 + fr) * 8;
                f16x8 bhn = *(const f16x8*)(L + 16384 + boff);
                f16x8 bln = *(const f16x8*)(L + 24576 + boff);
                __builtin_amdgcn_s_setprio(1);
                #pragma unroll
                for (int m = 0; m < 4; ++m)
                    acc[m][n] = __builtin_amdgcn_mfma_f32_16x16x32_f16(ah[m], bhn, acc[m][n], 0, 0, 0);
                #pragma unroll
                for (int m = 0; m < 4; ++m)
                    acc[m][n] = __builtin_amdgcn_mfma_f32_16x16x32_f16(ah[m], bln, acc[m][n], 0, 0, 0);
                #pragma unroll
                for (int m = 0; m < 4; ++m)
                    acc[m][n] = __builtin_amdgcn_mfma_f32_16x16x32_f16(al[m], bhn, acc[m][n], 0, 0, 0);
                __builtin_amdgcn_s_setprio(0);
            }
        }

        // epilogue: fold into running argmin (cols ascend in (ct, n) => '<' keeps first)
        float e2v[8];
        #pragma unroll
        for (int n = 0; n < 8; ++n) e2v[n] = e2[cb + wc * 128 + n * 16 + fr];
        #pragma unroll
        for (int m = 0; m < 4; ++m) {
            f32x4 x2v = *(const f32x4*)(x2 + m0 + wr * 64 + m * 16 + q * 4);
            #pragma unroll
            for (int j = 0; j < 4; ++j) {
                const int bi = m * 4 + j;
                #pragma unroll
                for (int n = 0; n < 8; ++n) {
                    float d = fmaf(acc[m][n][j], -0x1p-21f, x2v[j]) + e2v[n];
                    int c = cb + wc * 128 + n * 16 + fr;
                    if (d < bst[bi]) { bst[bi] = d; bix[bi] = c; }
                }
            }
        }
    }

    // merge the 16 lanes sharing each output row; ties -> lower col
    #pragma unroll
    for (int i = 0; i < 16; ++i) {
        float v = bst[i]; int idx = bix[i];
        #pragma unroll
        for (int off = 8; off >= 1; off >>= 1) {
            float ov = __shfl_xor(v, off, 64);
            int   oi = __shfl_xor(idx, off, 64);
            if (ov < v || (ov == v && oi < idx)) { v = ov; idx = oi; }
        }
        if (fr == 0) {
            int row = m0 + wr * 64 + (i >> 2) * 16 + q * 4 + (i & 3);
            int p = ch * 2 + wc;
            bestv[p * M_TOT + row] = v;
            besti[p * M_TOT + row] = idx;
        }
    }
}

// ---------- finalize: merge partials (explicit index tie-break), gather ----------
__global__ void finalize_kernel(const float* __restrict__ e,
                                const float* __restrict__ bestv,
                                const int* __restrict__ besti,
                                float* __restrict__ out, int npart)
{
    int m    = blockIdx.x * 4 + (threadIdx.x >> 6);
    int lane = threadIdx.x & 63;
    float bv = bestv[m]; int bi = besti[m];
    for (int h = 1; h < npart; ++h) {
        float v = bestv[h * M_TOT + m];
        int   i2 = besti[h * M_TOT + m];
        if (v < bv || (v == bv && i2 < bi)) { bv = v; bi = i2; }
    }
    if (lane == 0) out[QOFF + m] = (float)bi;
    float4 v = *(const float4*)(e + (size_t)bi * D_DIM + lane * 4);
    *(float4*)(out + (size_t)m * D_DIM + lane * 4) = v;
}

// ================= fallback fp32 path (only if ws too small) =================
#define BMm 128
#define BNn 128
#define BKk 16
#define BSW 144
#define NKT (D_DIM / BKk)
#define NCT (CCH / BNn)

__device__ __forceinline__ int pcol(int c) { return c + ((c >> 5) << 2); }

__global__ void sq_kernel(const float* __restrict__ x, const float* __restrict__ e,
                          float* __restrict__ x2, float* __restrict__ e2) {
    int row  = blockIdx.x * 4 + (threadIdx.x >> 6);
    int lane = threadIdx.x & 63;
    const float* src = (row < M_TOT) ? (x + (size_t)row * D_DIM)
                                     : (e + (size_t)(row - M_TOT) * D_DIM);
    float4 v = *(const float4*)(src + lane * 4);
    float s = v.x * v.x + v.y * v.y + v.z * v.z + v.w * v.w;
    #pragma unroll
    for (int off = 32; off >= 1; off >>= 1) s += __shfl_xor(s, off, 64);
    if (lane == 0) { if (row < M_TOT) x2[row] = s; else e2[row - M_TOT] = s; }
}

__global__ __launch_bounds__(256, 1) void dist_kernel(
    const float* __restrict__ x, const float* __restrict__ e,
    const float* __restrict__ x2, const float* __restrict__ e2,
    float* __restrict__ bestv, int* __restrict__ besti)
{
    __shared__ __align__(16) float As[2][BKk][BMm];
    __shared__ __align__(16) float Bs[2][BKk][BSW];
    const int t  = threadIdx.x;
    const int ty = t >> 4, tx = t & 15;
    const int mt = (int)blockIdx.x >> 2;
    const int ch = (int)blockIdx.x & 3;
    const int m0 = mt * BMm, c0 = ch * CCH;
    float x2r[8];
    #pragma unroll
    for (int i = 0; i < 8; ++i) x2r[i] = x2[m0 + ty * 8 + i];
    float best[8]; int bidx[8];
    #pragma unroll
    for (int i = 0; i < 8; ++i) { best[i] = 3.4e38f; bidx[i] = 0; }
    const int r0  = t >> 2;
    const int cq0 = (t & 3) << 2;
    for (int ct = 0; ct < NCT; ++ct) {
        const int cb = c0 + ct * BNn;
        float acc[8][8];
        #pragma unroll
        for (int i = 0; i < 8; ++i)
            #pragma unroll
            for (int j = 0; j < 8; ++j) acc[i][j] = 0.f;
        #pragma unroll
        for (int it = 0; it < 2; ++it) {
            int r = r0 + it * 64;
            float4 va = *(const float4*)(x + (size_t)(m0 + r) * D_DIM + cq0);
            float4 vb = *(const float4*)(e + (size_t)(cb + r) * D_DIM + cq0);
            As[0][cq0 + 0][r] = va.x; As[0][cq0 + 1][r] = va.y;
            As[0][cq0 + 2][r] = va.z; As[0][cq0 + 3][r] = va.w;
            int pr = pcol(r);
            Bs[0][cq0 + 0][pr] = vb.x; Bs[0][cq0 + 1][pr] = vb.y;
            Bs[0][cq0 + 2][pr] = vb.z; Bs[0][cq0 + 3][pr] = vb.w;
        }
        __syncthreads();
        #pragma unroll 1
        for (int kt = 0; kt < NKT; ++kt) {
            const int cur = kt & 1;
            float4 pa[2], pb[2];
            if (kt + 1 < NKT) {
                const int k0 = (kt + 1) * BKk;
                #pragma unroll
                for (int it = 0; it < 2; ++it) {
                    int r = r0 + it * 64;
                    pa[it] = *(const float4*)(x + (size_t)(m0 + r) * D_DIM + k0 + cq0);
                    pb[it] = *(const float4*)(e + (size_t)(cb + r) * D_DIM + k0 + cq0);
                }
            }
            #pragma unroll
            for (int k = 0; k < BKk; ++k) {
                float a[8], b[8];
                *(float4*)&a[0] = *(const float4*)&As[cur][k][ty * 8];
                *(float4*)&a[4] = *(const float4*)&As[cur][k][ty * 8 + 4];
                const int pb0 = pcol(tx * 8);
                *(float4*)&b[0] = *(const float4*)&Bs[cur][k][pb0];
                *(float4*)&b[4] = *(const float4*)&Bs[cur][k][pb0 + 4];
                #pragma unroll
                for (int i = 0; i < 8; ++i)
                    #pragma unroll
                    for (int j = 0; j < 8; ++j)
                        acc[i][j] = fmaf(a[i], b[j], acc[i][j]);
            }
            __syncthreads();
            if (kt + 1 < NKT) {
                const int nb = cur ^ 1;
                #pragma unroll
                for (int it = 0; it < 2; ++it) {
                    int r = r0 + it * 64;
                    As[nb][cq0 + 0][r] = pa[it].x; As[nb][cq0 + 1][r] = pa[it].y;
                    As[nb][cq0 + 2][r] = pa[it].z; As[nb][cq0 + 3][r] = pa[it].w;
                    int pr = pcol(r);
                    Bs[nb][cq0 + 0][pr] = pb[it].x; Bs[nb][cq0 + 1][pr] = pb[it].y;
                    Bs[nb][cq0 + 2][pr] = pb[it].z; Bs[nb][cq0 + 3][pr] = pb[it].w;
                }
                __syncthreads();
            }
        }
        float e2v[8];
        #pragma unroll
        for (int j = 0; j < 8; ++j) e2v[j] = e2[cb + tx * 8 + j];
        #pragma unroll
        for (int i = 0; i < 8; ++i) {
            #pragma unroll
            for (int j = 0; j < 8; ++j) {
                float d = (x2r[i] - 2.0f * acc[i][j]) + e2v[j];
                int c = cb + tx * 8 + j;
                if (d < best[i]) { best[i] = d; bidx[i] = c; }
            }
        }
    }
    #pragma unroll
    for (int i = 0; i < 8; ++i) {
        float v = best[i]; int idx = bidx[i];
        #pragma unroll
        for (int off = 8; off >= 1; off >>= 1) {
            float ov = __shfl_xor(v, off, 64);
            int   oi = __shfl_xor(idx, off, 64);
            if (ov < v || (ov == v && oi < idx)) { v = ov; idx = oi; }
        }
        if (tx == 0) {
            int row = m0 + ty * 8 + i;
            bestv[ch * M_TOT + row] = v;
            besti[ch * M_TOT + row] = idx;
        }
    }
}

extern "C" void kernel_launch(void* const* d_in, const int* in_sizes, int n_in,
                              void* d_out, int out_size, void* d_ws, size_t ws_size,
                              hipStream_t stream) {
    const float* x = (const float*)d_in[0];   // [16384, 256]
    const float* e = (const float*)d_in[1];   // [8192, 256]
    float* out = (float*)d_out;

    float* wsf   = (float*)d_ws;
    float* x2    = wsf + WS_X2;
    float* e2    = wsf + WS_E2;
    float* bestv = wsf + WS_BV;
    int*   besti = (int*)(wsf + WS_BI);

    if (ws_size >= WS_NEED) {
        f16* sp = (f16*)(wsf + WS_SPL);
        split_kernel<<<(M_TOT + C_TOT) / 4, 256, 0, stream>>>(x, e, sp, x2, e2);
        mdist_kernel<<<(M_TOT / 256) * NCH, 512, 0, stream>>>(sp, x2, e2, bestv, besti);
        finalize_kernel<<<M_TOT / 4, 256, 0, stream>>>(e, bestv, besti, out, NPART);
    } else {
        sq_kernel<<<(M_TOT + C_TOT) / 4, 256, 0, stream>>>(x, e, x2, e2);
        dist_kernel<<<(M_TOT / BMm) * NCH, 256, 0, stream>>>(x, e, x2, e2, bestv, besti);
        finalize_kernel<<<M_TOT / 4, 256, 0, stream>>>(e, bestv, besti, out, NCH);
    }
}

// Round 8
// 259.514 us; speedup vs baseline: 1.2454x; 1.0020x over previous
//
#include <hip/hip_runtime.h>
#include <hip/hip_bf16.h>

#define M_TOT 16384
#define D_DIM 256
#define C_TOT 8192
#define NCH 4
#define CCH (C_TOT / NCH)     // 2048
#define QOFF (M_TOT * D_DIM)
#define NPART 8               // 4 C-chunks x 2 wave-columns

typedef _Float16 f16;
typedef __attribute__((ext_vector_type(8))) _Float16 f16x8;
typedef __attribute__((ext_vector_type(4))) float f32x4;

// ---- workspace layout (float units) ----
#define WS_X2 0
#define WS_E2 (M_TOT)
#define WS_BV (M_TOT + C_TOT)
#define WS_BI (WS_BV + NPART * M_TOT)
#define WS_SPL (WS_BI + NPART * M_TOT)
// half-unit offsets within the split region
#define XH_OFF ((size_t)0)
#define XL_OFF ((size_t)M_TOT * D_DIM)
#define EH_OFF ((size_t)2 * M_TOT * D_DIM)
#define EL_OFF ((size_t)2 * M_TOT * D_DIM + (size_t)C_TOT * D_DIM)
#define SPL_HALFS ((size_t)2 * M_TOT * D_DIM + (size_t)2 * C_TOT * D_DIM)
#define WS_NEED ((size_t)WS_SPL * 4 + SPL_HALFS * 2)

__device__ __forceinline__ void gll16(const void* g, void* l) {
    __builtin_amdgcn_global_load_lds((const __attribute__((address_space(1))) void*)g,
                                     (__attribute__((address_space(3))) void*)l, 16, 0, 0);
}

// ---------- split: fp16 (hi,lo) decomposition + row sums of squares ----------
__global__ void split_kernel(const float* __restrict__ x, const float* __restrict__ e,
                             f16* __restrict__ sp, float* __restrict__ x2, float* __restrict__ e2)
{
    int row  = blockIdx.x * 4 + (threadIdx.x >> 6);
    int lane = threadIdx.x & 63;
    bool isx = row < M_TOT;
    int r = isx ? row : row - M_TOT;
    const float* src = (isx ? x : e) + (size_t)r * D_DIM;
    float4 v = *(const float4*)(src + lane * 4);
    float s = v.x * v.x + v.y * v.y + v.z * v.z + v.w * v.w;  // ORIGINAL scale
    #pragma unroll
    for (int off = 32; off >= 1; off >>= 1) s += __shfl_xor(s, off, 64);
    float sc = isx ? 256.0f : 16384.0f;
    float a[4] = {v.x * sc, v.y * sc, v.z * sc, v.w * sc};
    union { f16 h[4]; ushort4 u; } hh, ll;
    #pragma unroll
    for (int i = 0; i < 4; ++i) {
        f16 h = (f16)a[i];
        hh.h[i] = h;
        ll.h[i] = (f16)(a[i] - (float)h);
    }
    size_t base = (size_t)r * D_DIM + lane * 4;
    f16* ph = sp + (isx ? XH_OFF : EH_OFF) + base;
    f16* pl = sp + (isx ? XL_OFF : EL_OFF) + base;
    *(ushort4*)ph = hh.u;
    *(ushort4*)pl = ll.u;
    if (lane == 0) { if (isx) x2[r] = s; else e2[r] = s; }
}

// ---------- MFMA distance + fused argmin ----------
// 256x256 block tile, 8 waves (4x2: 64x128 per wave), BK=32, 3-term fp16 split
// GEMM S = xh*eh + xh*el + xl*eh; d = fma(S, -2^-21, x2) + e2.
// R7 skeleton (single vmcnt(0)+barrier per kt). This round: x2 hoist dropped
// (frees 16 VGPR) + explicit 2-deep named-register pipeline on b-fragments so
// the scheduler overlaps ds_read latency with the MFMA cluster.
__global__ __launch_bounds__(512, 2) void mdist_kernel(
    const f16* __restrict__ sp, const float* __restrict__ x2, const float* __restrict__ e2,
    float* __restrict__ bestv, int* __restrict__ besti)
{
    __shared__ __align__(16) f16 lds[65536];  // 128 KB

    const int t  = threadIdx.x;          // 0..511
    const int l  = t & 63;
    const int wv = t >> 6;               // 0..7
    const int wr = wv >> 1, wc = wv & 1; // 4x2 wave grid: rows wr*64, cols wc*128
    const int mt = (int)blockIdx.x >> 2;
    const int ch = (int)blockIdx.x & 3;
    const int m0 = mt * 256, c0 = ch * CCH;

    const int q  = l >> 4;   // fragment k-block / row-quad (0..3)
    const int fr = l & 15;

    // staging: unit = (tensor tn, kb, rowblk rb); wvh selects kb phase, rb=wv&3
    const int wvh = wv >> 2, rb = wv & 3;
    const f16* gxh = sp + XH_OFF + (size_t)(m0 + rb * 64 + l) * D_DIM;
    const f16* gxl = sp + XL_OFF + (size_t)(m0 + rb * 64 + l) * D_DIM;
    const f16* geh = sp + EH_OFF + (size_t)(c0 + rb * 64 + l) * D_DIM;
    const f16* gel = sp + EL_OFF + (size_t)(c0 + rb * 64 + l) * D_DIM;
    char* lbase = (char*)&lds[0] + rb * 1024 + l * 16;

#define KB(it) ((2 * (it) + wvh) & 3)
    auto STAGE = [&](int buf, int ktv, int ctv) {
        const size_t ko = (size_t)ktv * 32;
        const size_t co = (size_t)ctv * 256 * D_DIM + ko;
        char* lb = lbase + buf * 65536;
        gll16(gxh + ko + KB(0) * 8, lb + 0 * 16384 + KB(0) * 4096);
        gll16(gxh + ko + KB(1) * 8, lb + 0 * 16384 + KB(1) * 4096);
        gll16(gxl + ko + KB(2) * 8, lb + 1 * 16384 + KB(2) * 4096);
        gll16(gxl + ko + KB(3) * 8, lb + 1 * 16384 + KB(3) * 4096);
        gll16(geh + co + KB(4) * 8, lb + 2 * 16384 + KB(4) * 4096);
        gll16(geh + co + KB(5) * 8, lb + 2 * 16384 + KB(5) * 4096);
        gll16(gel + co + KB(6) * 8, lb + 3 * 16384 + KB(6) * 4096);
        gll16(gel + co + KB(7) * 8, lb + 3 * 16384 + KB(7) * 4096);
    };

    float bst[16]; int bix[16];
    #pragma unroll
    for (int i = 0; i < 16; ++i) { bst[i] = 3.4e38f; bix[i] = 0; }

    STAGE(0, 0, 0);

    for (int ct = 0; ct < 8; ++ct) {
        const int cb = c0 + ct * 256;
        f32x4 acc[4][8];
        #pragma unroll
        for (int m = 0; m < 4; ++m)
            #pragma unroll
            for (int n = 0; n < 8; ++n)
                #pragma unroll
                for (int k = 0; k < 4; ++k) acc[m][n][k] = 0.f;

        #pragma unroll 1
        for (int kt = 0; kt < 8; ++kt) {
            const int cur = kt & 1;
            // drain LDS-DMA that staged lds[cur] (race-proven R3/R5/R7 skeleton)
            asm volatile("s_waitcnt vmcnt(0)" ::: "memory");
            __syncthreads();
            __builtin_amdgcn_sched_barrier(0);

            if (kt < 7)       STAGE(cur ^ 1, kt + 1, ct);
            else if (ct < 7)  STAGE(cur ^ 1, 0, ct + 1);

            const f16* L = &lds[0] + cur * 32768;  // halfs

            // A fragments for this kt: 8 x f16x8 = 16 VGPR
            f16x8 ah[4], al[4];
            #pragma unroll
            for (int m = 0; m < 4; ++m) {
                int aoff = (q * 256 + wr * 64 + m * 16 + fr) * 8;
                ah[m] = *(const f16x8*)(L + aoff);
                al[m] = *(const f16x8*)(L + 8192 + aoff);
            }
            // 2-deep named-register pipeline on b-fragments (static renaming
            // under full unroll): read n+1 before the MFMA cluster of n.
#define BOFF(n) ((q * 256 + wc * 128 + (n) * 16 + fr) * 8)
            f16x8 bhA = *(const f16x8*)(L + 16384 + BOFF(0));
            f16x8 blA = *(const f16x8*)(L + 24576 + BOFF(0));
            #pragma unroll
            for (int n = 0; n < 8; ++n) {
                f16x8 bhB, blB;
                if (n < 7) {
                    bhB = *(const f16x8*)(L + 16384 + BOFF(n + 1));
                    blB = *(const f16x8*)(L + 24576 + BOFF(n + 1));
                }
                __builtin_amdgcn_s_setprio(1);
                #pragma unroll
                for (int m = 0; m < 4; ++m)
                    acc[m][n] = __builtin_amdgcn_mfma_f32_16x16x32_f16(ah[m], bhA, acc[m][n], 0, 0, 0);
                #pragma unroll
                for (int m = 0; m < 4; ++m)
                    acc[m][n] = __builtin_amdgcn_mfma_f32_16x16x32_f16(ah[m], blA, acc[m][n], 0, 0, 0);
                #pragma unroll
                for (int m = 0; m < 4; ++m)
                    acc[m][n] = __builtin_amdgcn_mfma_f32_16x16x32_f16(al[m], bhA, acc[m][n], 0, 0, 0);
                __builtin_amdgcn_s_setprio(0);
                bhA = bhB; blA = blB;  // SSA rename (full unroll)
            }
#undef BOFF
        }

        // epilogue: fold into running argmin (cols ascend in (ct, n) => '<' keeps first)
        float e2v[8];
        #pragma unroll
        for (int n = 0; n < 8; ++n) e2v[n] = e2[cb + wc * 128 + n * 16 + fr];
        #pragma unroll
        for (int m = 0; m < 4; ++m) {
            f32x4 x2v = *(const f32x4*)(x2 + m0 + wr * 64 + m * 16 + q * 4);
            #pragma unroll
            for (int j = 0; j < 4; ++j) {
                const int bi = m * 4 + j;
                #pragma unroll
                for (int n = 0; n < 8; ++n) {
                    float d = fmaf(acc[m][n][j], -0x1p-21f, x2v[j]) + e2v[n];
                    int c = cb + wc * 128 + n * 16 + fr;
                    if (d < bst[bi]) { bst[bi] = d; bix[bi] = c; }
                }
            }
        }
    }

    // merge the 16 lanes sharing each output row; ties -> lower col
    #pragma unroll
    for (int i = 0; i < 16; ++i) {
        float v = bst[i]; int idx = bix[i];
        #pragma unroll
        for (int off = 8; off >= 1; off >>= 1) {
            float ov = __shfl_xor(v, off, 64);
            int   oi = __shfl_xor(idx, off, 64);
            if (ov < v || (ov == v && oi < idx)) { v = ov; idx = oi; }
        }
        if (fr == 0) {
            int row = m0 + wr * 64 + (i >> 2) * 16 + q * 4 + (i & 3);
            int p = ch * 2 + wc;
            bestv[p * M_TOT + row] = v;
            besti[p * M_TOT + row] = idx;
        }
    }
}

// ---------- finalize: merge partials (explicit index tie-break), gather ----------
__global__ void finalize_kernel(const float* __restrict__ e,
                                const float* __restrict__ bestv,
                                const int* __restrict__ besti,
                                float* __restrict__ out, int npart)
{
    int m    = blockIdx.x * 4 + (threadIdx.x >> 6);
    int lane = threadIdx.x & 63;
    float bv = bestv[m]; int bi = besti[m];
    for (int h = 1; h < npart; ++h) {
        float v = bestv[h * M_TOT + m];
        int   i2 = besti[h * M_TOT + m];
        if (v < bv || (v == bv && i2 < bi)) { bv = v; bi = i2; }
    }
    if (lane == 0) out[QOFF + m] = (float)bi;
    float4 v = *(const float4*)(e + (size_t)bi * D_DIM + lane * 4);
    *(float4*)(out + (size_t)m * D_DIM + lane * 4) = v;
}

// ================= fallback fp32 path (only if ws too small) =================
#define BMm 128
#define BNn 128
#define BKk 16
#define BSW 144
#define NKT (D_DIM / BKk)
#define NCT (CCH / BNn)

__device__ __forceinline__ int pcol(int c) { return c + ((c >> 5) << 2); }

__global__ void sq_kernel(const float* __restrict__ x, const float* __restrict__ e,
                          float* __restrict__ x2, float* __restrict__ e2) {
    int row  = blockIdx.x * 4 + (threadIdx.x >> 6);
    int lane = threadIdx.x & 63;
    const float* src = (row < M_TOT) ? (x + (size_t)row * D_DIM)
                                     : (e + (size_t)(row - M_TOT) * D_DIM);
    float4 v = *(const float4*)(src + lane * 4);
    float s = v.x * v.x + v.y * v.y + v.z * v.z + v.w * v.w;
    #pragma unroll
    for (int off = 32; off >= 1; off >>= 1) s += __shfl_xor(s, off, 64);
    if (lane == 0) { if (row < M_TOT) x2[row] = s; else e2[row - M_TOT] = s; }
}

__global__ __launch_bounds__(256, 1) void dist_kernel(
    const float* __restrict__ x, const float* __restrict__ e,
    const float* __restrict__ x2, const float* __restrict__ e2,
    float* __restrict__ bestv, int* __restrict__ besti)
{
    __shared__ __align__(16) float As[2][BKk][BMm];
    __shared__ __align__(16) float Bs[2][BKk][BSW];
    const int t  = threadIdx.x;
    const int ty = t >> 4, tx = t & 15;
    const int mt = (int)blockIdx.x >> 2;
    const int ch = (int)blockIdx.x & 3;
    const int m0 = mt * BMm, c0 = ch * CCH;
    float x2r[8];
    #pragma unroll
    for (int i = 0; i < 8; ++i) x2r[i] = x2[m0 + ty * 8 + i];
    float best[8]; int bidx[8];
    #pragma unroll
    for (int i = 0; i < 8; ++i) { best[i] = 3.4e38f; bidx[i] = 0; }
    const int r0  = t >> 2;
    const int cq0 = (t & 3) << 2;
    for (int ct = 0; ct < NCT; ++ct) {
        const int cb = c0 + ct * BNn;
        float acc[8][8];
        #pragma unroll
        for (int i = 0; i < 8; ++i)
            #pragma unroll
            for (int j = 0; j < 8; ++j) acc[i][j] = 0.f;
        #pragma unroll
        for (int it = 0; it < 2; ++it) {
            int r = r0 + it * 64;
            float4 va = *(const float4*)(x + (size_t)(m0 + r) * D_DIM + cq0);
            float4 vb = *(const float4*)(e + (size_t)(cb + r) * D_DIM + cq0);
            As[0][cq0 + 0][r] = va.x; As[0][cq0 + 1][r] = va.y;
            As[0][cq0 + 2][r] = va.z; As[0][cq0 + 3][r] = va.w;
            int pr = pcol(r);
            Bs[0][cq0 + 0][pr] = vb.x; Bs[0][cq0 + 1][pr] = vb.y;
            Bs[0][cq0 + 2][pr] = vb.z; Bs[0][cq0 + 3][pr] = vb.w;
        }
        __syncthreads();
        #pragma unroll 1
        for (int kt = 0; kt < NKT; ++kt) {
            const int cur = kt & 1;
            float4 pa[2], pb[2];
            if (kt + 1 < NKT) {
                const int k0 = (kt + 1) * BKk;
                #pragma unroll
                for (int it = 0; it < 2; ++it) {
                    int r = r0 + it * 64;
                    pa[it] = *(const float4*)(x + (size_t)(m0 + r) * D_DIM + k0 + cq0);
                    pb[it] = *(const float4*)(e + (size_t)(cb + r) * D_DIM + k0 + cq0);
                }
            }
            #pragma unroll
            for (int k = 0; k < BKk; ++k) {
                float a[8], b[8];
                *(float4*)&a[0] = *(const float4*)&As[cur][k][ty * 8];
                *(float4*)&a[4] = *(const float4*)&As[cur][k][ty * 8 + 4];
                const int pb0 = pcol(tx * 8);
                *(float4*)&b[0] = *(const float4*)&Bs[cur][k][pb0];
                *(float4*)&b[4] = *(const float4*)&Bs[cur][k][pb0 + 4];
                #pragma unroll
                for (int i = 0; i < 8; ++i)
                    #pragma unroll
                    for (int j = 0; j < 8; ++j)
                        acc[i][j] = fmaf(a[i], b[j], acc[i][j]);
            }
            __syncthreads();
            if (kt + 1 < NKT) {
                const int nb = cur ^ 1;
                #pragma unroll
                for (int it = 0; it < 2; ++it) {
                    int r = r0 + it * 64;
                    As[nb][cq0 + 0][r] = pa[it].x; As[nb][cq0 + 1][r] = pa[it].y;
                    As[nb][cq0 + 2][r] = pa[it].z; As[nb][cq0 + 3][r] = pa[it].w;
                    int pr = pcol(r);
                    Bs[nb][cq0 + 0][pr] = pb[it].x; Bs[nb][cq0 + 1][pr] = pb[it].y;
                    Bs[nb][cq0 + 2][pr] = pb[it].z; Bs[nb][cq0 + 3][pr] = pb[it].w;
                }
                __syncthreads();
            }
        }
        float e2v[8];
        #pragma unroll
        for (int j = 0; j < 8; ++j) e2v[j] = e2[cb + tx * 8 + j];
        #pragma unroll
        for (int i = 0; i < 8; ++i) {
            #pragma unroll
            for (int j = 0; j < 8; ++j) {
                float d = (x2r[i] - 2.0f * acc[i][j]) + e2v[j];
                int c = cb + tx * 8 + j;
                if (d < best[i]) { best[i] = d; bidx[i] = c; }
            }
        }
    }
    #pragma unroll
    for (int i = 0; i < 8; ++i) {
        float v = best[i]; int idx = bidx[i];
        #pragma unroll
        for (int off = 8; off >= 1; off >>= 1) {
            float ov = __shfl_xor(v, off, 64);
            int   oi = __shfl_xor(idx, off, 64);
            if (ov < v || (ov == v && oi < idx)) { v = ov; idx = oi; }
        }
        if (tx == 0) {
            int row = m0 + ty * 8 + i;
            bestv[ch * M_TOT + row] = v;
            besti[ch * M_TOT + row] = idx;
        }
    }
}

extern "C" void kernel_launch(void* const* d_in, const int* in_sizes, int n_in,
                              void* d_out, int out_size, void* d_ws, size_t ws_size,
                              hipStream_t stream) {
    const float* x = (const float*)d_in[0];   // [16384, 256]
    const float* e = (const float*)d_in[1];   // [8192, 256]
    float* out = (float*)d_out;

    float* wsf   = (float*)d_ws;
    float* x2    = wsf + WS_X2;
    float* e2    = wsf + WS_E2;
    float* bestv = wsf + WS_BV;
    int*   besti = (int*)(wsf + WS_BI);

    if (ws_size >= WS_NEED) {
        f16* sp = (f16*)(wsf + WS_SPL);
        split_kernel<<<(M_TOT + C_TOT) / 4, 256, 0, stream>>>(x, e, sp, x2, e2);
        mdist_kernel<<<(M_TOT / 256) * NCH, 512, 0, stream>>>(sp, x2, e2, bestv, besti);
        finalize_kernel<<<M_TOT / 4, 256, 0, stream>>>(e, bestv, besti, out, NPART);
    } else {
        sq_kernel<<<(M_TOT + C_TOT) / 4, 256, 0, stream>>>(x, e, x2, e2);
        dist_kernel<<<(M_TOT / BMm) * NCH, 256, 0, stream>>>(x, e, x2, e2, bestv, besti);
        finalize_kernel<<<M_TOT / 4, 256, 0, stream>>>(e, bestv, besti, out, NCH);
    }
}

// Round 9
// 224.949 us; speedup vs baseline: 1.4368x; 1.1537x over previous
//
#include <hip/hip_runtime.h>
#include <hip/hip_bf16.h>

#define M_TOT 16384
#define D_DIM 256
#define C_TOT 8192
#define NCH 4
#define CCH (C_TOT / NCH)     // 2048
#define QOFF (M_TOT * D_DIM)
#define NPART 8               // 4 C-chunks x 2 wave-columns

typedef _Float16 f16;
typedef __attribute__((ext_vector_type(8))) _Float16 f16x8;
typedef __attribute__((ext_vector_type(4))) float f32x4;

// ---- workspace layout (float units) ----
#define WS_X2 0
#define WS_E2 (M_TOT)
#define WS_BV (M_TOT + C_TOT)
#define WS_BI (WS_BV + NPART * M_TOT)
#define WS_SPL (WS_BI + NPART * M_TOT)
// half-unit offsets within the split region
#define XH_OFF ((size_t)0)
#define XL_OFF ((size_t)M_TOT * D_DIM)
#define EH_OFF ((size_t)2 * M_TOT * D_DIM)
#define EL_OFF ((size_t)2 * M_TOT * D_DIM + (size_t)C_TOT * D_DIM)
#define SPL_HALFS ((size_t)2 * M_TOT * D_DIM + (size_t)2 * C_TOT * D_DIM)
#define WS_NEED ((size_t)WS_SPL * 4 + SPL_HALFS * 2)

__device__ __forceinline__ void gll16(const void* g, void* l) {
    __builtin_amdgcn_global_load_lds((const __attribute__((address_space(1))) void*)g,
                                     (__attribute__((address_space(3))) void*)l, 16, 0, 0);
}

// ---------- split: fp16 (hi,lo) decomposition + row sums of squares ----------
__global__ void split_kernel(const float* __restrict__ x, const float* __restrict__ e,
                             f16* __restrict__ sp, float* __restrict__ x2, float* __restrict__ e2)
{
    int row  = blockIdx.x * 4 + (threadIdx.x >> 6);
    int lane = threadIdx.x & 63;
    bool isx = row < M_TOT;
    int r = isx ? row : row - M_TOT;
    const float* src = (isx ? x : e) + (size_t)r * D_DIM;
    float4 v = *(const float4*)(src + lane * 4);
    float s = v.x * v.x + v.y * v.y + v.z * v.z + v.w * v.w;  // ORIGINAL scale
    #pragma unroll
    for (int off = 32; off >= 1; off >>= 1) s += __shfl_xor(s, off, 64);
    float sc = isx ? 256.0f : 16384.0f;
    float a[4] = {v.x * sc, v.y * sc, v.z * sc, v.w * sc};
    union { f16 h[4]; ushort4 u; } hh, ll;
    #pragma unroll
    for (int i = 0; i < 4; ++i) {
        f16 h = (f16)a[i];
        hh.h[i] = h;
        ll.h[i] = (f16)(a[i] - (float)h);
    }
    size_t base = (size_t)r * D_DIM + lane * 4;
    f16* ph = sp + (isx ? XH_OFF : EH_OFF) + base;
    f16* pl = sp + (isx ? XL_OFF : EL_OFF) + base;
    *(ushort4*)ph = hh.u;
    *(ushort4*)pl = ll.u;
    if (lane == 0) { if (isx) x2[r] = s; else e2[r] = s; }
}

// ---------- MFMA distance + fused argmin ----------
// 256x256 block tile, 8 waves (4x2: 64x128 per wave), BK=32, 3-term fp16 split
// GEMM S = xh*eh + xh*el + xl*eh; d = fma(S, -2^-21, x2) + e2.
// 4-phase counted-vmcnt schedule (T3+T4), RAW s_barrier (NOT __syncthreads —
// __syncthreads drains vmcnt(0), which killed R6's counted waits):
//   per kt: 4 phases of 24 MFMA; stage split 5/1/1/1 lines, issued 4 phases
//   ahead of consumption; waits vmcnt(3)/vmcnt(7)/(7)/(7) — never 0 in loop.
// LDS per buffer (32K halfs): xh@0, xl@8192, eh@16384, el@24576;
// A layout (kb*256+row)*8; B layout re-blocked [p][kb][wc][w] so each
// phase-slice is DMA-contiguous per wave (linear dest + per-lane global src).
__global__ __launch_bounds__(512, 2) void mdist_kernel(
    const f16* __restrict__ sp, const float* __restrict__ x2, const float* __restrict__ e2,
    float* __restrict__ bestv, int* __restrict__ besti)
{
    __shared__ __align__(16) f16 lds[65536];  // 128 KB

    const int t  = threadIdx.x;          // 0..511
    const int l  = t & 63;
    const int wv = t >> 6;               // 0..7
    const int wr = wv >> 1, wc = wv & 1; // 4x2 wave grid: rows wr*64, cols wc*128
    const int mt = (int)blockIdx.x >> 2;
    const int ch = (int)blockIdx.x & 3;
    const int m0 = mt * 256, c0 = ch * CCH;

    const int q  = l >> 4;   // fragment k-block (0..3)
    const int fr = l & 15;

    // A staging: wvh in {0,1} picks kb pair, rb in {0..3} picks row-block
    const int wvh = wv >> 2, rb = wv & 3;
    const f16* gxh = sp + XH_OFF + (size_t)(m0 + rb * 64 + l) * D_DIM;
    const f16* gxl = sp + XL_OFF + (size_t)(m0 + rb * 64 + l) * D_DIM;
    // B staging: waves 0-3 -> eh, 4-7 -> el; kb = wv&3; lane -> (wc=l>>5, w=l&31)
    const int bkb = wv & 3;
    const f16* gB = sp + ((wv < 4) ? EH_OFF : EL_OFF)
                    + (size_t)(c0 + (l >> 5) * 128 + (l & 31)) * D_DIM;
    const int btn_b = (wv < 4) ? 32768 : 49152;  // byte base within buffer

    auto STAGE_A = [&](int buf, int ktv) {       // 4 gll16-lines (xh, xl)
        char* lb = (char*)&lds[0] + buf * 65536;
        #pragma unroll
        for (int j = 0; j < 2; ++j) {
            int kb = j * 2 + wvh;
            gll16(gxh + ktv * 32 + kb * 8, lb + 0     + kb * 4096 + rb * 1024 + l * 16);
        }
        #pragma unroll
        for (int j = 0; j < 2; ++j) {
            int kb = j * 2 + wvh;
            gll16(gxl + ktv * 32 + kb * 8, lb + 16384 + kb * 4096 + rb * 1024 + l * 16);
        }
    };
    auto STAGE_B = [&](int buf, int ktv, int ctv, int p) {  // 1 gll16-line (slice p)
        char* lb = (char*)&lds[0] + buf * 65536;
        gll16(gB + (size_t)(ctv * 256 + 32 * p) * D_DIM + ktv * 32 + bkb * 8,
              lb + btn_b + p * 4096 + bkb * 1024 + l * 16);
    };

    float bst[16]; int bix[16];
    #pragma unroll
    for (int i = 0; i < 16; ++i) { bst[i] = 3.4e38f; bix[i] = 0; }

    // prologue: stage (ct=0,kt=0) into buf0, issue order [ph0:5][ph1][ph2][ph3]
    STAGE_A(0, 0);
    STAGE_B(0, 0, 0, 0);
    STAGE_B(0, 0, 0, 1);
    STAGE_B(0, 0, 0, 2);
    STAGE_B(0, 0, 0, 3);

    for (int ct = 0; ct < 8; ++ct) {
        const int cb = c0 + ct * 256;
        f32x4 acc[4][8];
        #pragma unroll
        for (int m = 0; m < 4; ++m)
            #pragma unroll
            for (int n = 0; n < 8; ++n)
                #pragma unroll
                for (int k = 0; k < 4; ++k) acc[m][n][k] = 0.f;

        #pragma unroll 1
        for (int kt = 0; kt < 8; ++kt) {
            const int cur = (ct * 8 + kt) & 1;
            const f16* L = &lds[0] + cur * 32768;  // halfs
            const int nbuf = cur ^ 1;
            int nkt = kt + 1, nct = ct;
            if (nkt == 8) { nkt = 0; nct = (ct + 1) & 7; }  // tail waste, keeps counts uniform

            f16x8 ah[4], al[4];

            #pragma unroll
            for (int p = 0; p < 4; ++p) {
                // counted wait: ph0 needs the 5 oldest lines (A + slice0) done,
                // ph1-3 need 1 more each; 3..7 newer lines stay in flight.
                if (p == 0) asm volatile("s_waitcnt vmcnt(3)" ::: "memory");
                else        asm volatile("s_waitcnt vmcnt(7)" ::: "memory");
                __builtin_amdgcn_s_barrier();          // RAW barrier — no implicit drain
                __builtin_amdgcn_sched_barrier(0);     // pin: nothing hoisted above

                if (p == 0) STAGE_A(nbuf, nkt);
                STAGE_B(nbuf, nkt, nct, p);

                if (p == 0) {
                    #pragma unroll
                    for (int m = 0; m < 4; ++m) {
                        int aoff = (q * 256 + wr * 64 + m * 16 + fr) * 8;
                        ah[m] = *(const f16x8*)(L + aoff);
                        al[m] = *(const f16x8*)(L + 8192 + aoff);
                    }
                }
                // B phase-slice reads: layout 16384 + p*2048 + kb*512 + wc*256 + w*8
                const int bbase = 16384 + p * 2048 + q * 512 + wc * 256;
                f16x8 bh0 = *(const f16x8*)(L + bbase        + (fr)      * 8);
                f16x8 bh1 = *(const f16x8*)(L + bbase        + (16 + fr) * 8);
                f16x8 bl0 = *(const f16x8*)(L + bbase + 8192 + (fr)      * 8);
                f16x8 bl1 = *(const f16x8*)(L + bbase + 8192 + (16 + fr) * 8);
                const int n0 = 2 * p, n1 = 2 * p + 1;

                __builtin_amdgcn_s_setprio(1);
                #pragma unroll
                for (int m = 0; m < 4; ++m)
                    acc[m][n0] = __builtin_amdgcn_mfma_f32_16x16x32_f16(ah[m], bh0, acc[m][n0], 0, 0, 0);
                #pragma unroll
                for (int m = 0; m < 4; ++m)
                    acc[m][n1] = __builtin_amdgcn_mfma_f32_16x16x32_f16(ah[m], bh1, acc[m][n1], 0, 0, 0);
                #pragma unroll
                for (int m = 0; m < 4; ++m)
                    acc[m][n0] = __builtin_amdgcn_mfma_f32_16x16x32_f16(ah[m], bl0, acc[m][n0], 0, 0, 0);
                #pragma unroll
                for (int m = 0; m < 4; ++m)
                    acc[m][n1] = __builtin_amdgcn_mfma_f32_16x16x32_f16(ah[m], bl1, acc[m][n1], 0, 0, 0);
                #pragma unroll
                for (int m = 0; m < 4; ++m)
                    acc[m][n0] = __builtin_amdgcn_mfma_f32_16x16x32_f16(al[m], bh0, acc[m][n0], 0, 0, 0);
                #pragma unroll
                for (int m = 0; m < 4; ++m)
                    acc[m][n1] = __builtin_amdgcn_mfma_f32_16x16x32_f16(al[m], bh1, acc[m][n1], 0, 0, 0);
                __builtin_amdgcn_s_setprio(0);
            }
        }

        // epilogue: fold into running argmin (cols ascend in (ct, n) => '<' keeps first)
        float e2v[8];
        #pragma unroll
        for (int n = 0; n < 8; ++n) e2v[n] = e2[cb + wc * 128 + n * 16 + fr];
        #pragma unroll
        for (int m = 0; m < 4; ++m) {
            f32x4 x2v = *(const f32x4*)(x2 + m0 + wr * 64 + m * 16 + q * 4);
            #pragma unroll
            for (int j = 0; j < 4; ++j) {
                const int bi = m * 4 + j;
                #pragma unroll
                for (int n = 0; n < 8; ++n) {
                    float d = fmaf(acc[m][n][j], -0x1p-21f, x2v[j]) + e2v[n];
                    int c = cb + wc * 128 + n * 16 + fr;
                    if (d < bst[bi]) { bst[bi] = d; bix[bi] = c; }
                }
            }
        }
    }

    // merge the 16 lanes sharing each output row; ties -> lower col
    #pragma unroll
    for (int i = 0; i < 16; ++i) {
        float v = bst[i]; int idx = bix[i];
        #pragma unroll
        for (int off = 8; off >= 1; off >>= 1) {
            float ov = __shfl_xor(v, off, 64);
            int   oi = __shfl_xor(idx, off, 64);
            if (ov < v || (ov == v && oi < idx)) { v = ov; idx = oi; }
        }
        if (fr == 0) {
            int row = m0 + wr * 64 + (i >> 2) * 16 + q * 4 + (i & 3);
            int p = ch * 2 + wc;
            bestv[p * M_TOT + row] = v;
            besti[p * M_TOT + row] = idx;
        }
    }
}

// ---------- finalize: merge partials (explicit index tie-break), gather ----------
__global__ void finalize_kernel(const float* __restrict__ e,
                                const float* __restrict__ bestv,
                                const int* __restrict__ besti,
                                float* __restrict__ out, int npart)
{
    int m    = blockIdx.x * 4 + (threadIdx.x >> 6);
    int lane = threadIdx.x & 63;
    float bv = bestv[m]; int bi = besti[m];
    for (int h = 1; h < npart; ++h) {
        float v = bestv[h * M_TOT + m];
        int   i2 = besti[h * M_TOT + m];
        if (v < bv || (v == bv && i2 < bi)) { bv = v; bi = i2; }
    }
    if (lane == 0) out[QOFF + m] = (float)bi;
    float4 v = *(const float4*)(e + (size_t)bi * D_DIM + lane * 4);
    *(float4*)(out + (size_t)m * D_DIM + lane * 4) = v;
}

// ================= fallback fp32 path (only if ws too small) =================
#define BMm 128
#define BNn 128
#define BKk 16
#define BSW 144
#define NKT (D_DIM / BKk)
#define NCT (CCH / BNn)

__device__ __forceinline__ int pcol(int c) { return c + ((c >> 5) << 2); }

__global__ void sq_kernel(const float* __restrict__ x, const float* __restrict__ e,
                          float* __restrict__ x2, float* __restrict__ e2) {
    int row  = blockIdx.x * 4 + (threadIdx.x >> 6);
    int lane = threadIdx.x & 63;
    const float* src = (row < M_TOT) ? (x + (size_t)row * D_DIM)
                                     : (e + (size_t)(row - M_TOT) * D_DIM);
    float4 v = *(const float4*)(src + lane * 4);
    float s = v.x * v.x + v.y * v.y + v.z * v.z + v.w * v.w;
    #pragma unroll
    for (int off = 32; off >= 1; off >>= 1) s += __shfl_xor(s, off, 64);
    if (lane == 0) { if (row < M_TOT) x2[row] = s; else e2[row - M_TOT] = s; }
}

__global__ __launch_bounds__(256, 1) void dist_kernel(
    const float* __restrict__ x, const float* __restrict__ e,
    const float* __restrict__ x2, const float* __restrict__ e2,
    float* __restrict__ bestv, int* __restrict__ besti)
{
    __shared__ __align__(16) float As[2][BKk][BMm];
    __shared__ __align__(16) float Bs[2][BKk][BSW];
    const int t  = threadIdx.x;
    const int ty = t >> 4, tx = t & 15;
    const int mt = (int)blockIdx.x >> 2;
    const int ch = (int)blockIdx.x & 3;
    const int m0 = mt * BMm, c0 = ch * CCH;
    float x2r[8];
    #pragma unroll
    for (int i = 0; i < 8; ++i) x2r[i] = x2[m0 + ty * 8 + i];
    float best[8]; int bidx[8];
    #pragma unroll
    for (int i = 0; i < 8; ++i) { best[i] = 3.4e38f; bidx[i] = 0; }
    const int r0  = t >> 2;
    const int cq0 = (t & 3) << 2;
    for (int ct = 0; ct < NCT; ++ct) {
        const int cb = c0 + ct * BNn;
        float acc[8][8];
        #pragma unroll
        for (int i = 0; i < 8; ++i)
            #pragma unroll
            for (int j = 0; j < 8; ++j) acc[i][j] = 0.f;
        #pragma unroll
        for (int it = 0; it < 2; ++it) {
            int r = r0 + it * 64;
            float4 va = *(const float4*)(x + (size_t)(m0 + r) * D_DIM + cq0);
            float4 vb = *(const float4*)(e + (size_t)(cb + r) * D_DIM + cq0);
            As[0][cq0 + 0][r] = va.x; As[0][cq0 + 1][r] = va.y;
            As[0][cq0 + 2][r] = va.z; As[0][cq0 + 3][r] = va.w;
            int pr = pcol(r);
            Bs[0][cq0 + 0][pr] = vb.x; Bs[0][cq0 + 1][pr] = vb.y;
            Bs[0][cq0 + 2][pr] = vb.z; Bs[0][cq0 + 3][pr] = vb.w;
        }
        __syncthreads();
        #pragma unroll 1
        for (int kt = 0; kt < NKT; ++kt) {
            const int cur = kt & 1;
            float4 pa[2], pb[2];
            if (kt + 1 < NKT) {
                const int k0 = (kt + 1) * BKk;
                #pragma unroll
                for (int it = 0; it < 2; ++it) {
                    int r = r0 + it * 64;
                    pa[it] = *(const float4*)(x + (size_t)(m0 + r) * D_DIM + k0 + cq0);
                    pb[it] = *(const float4*)(e + (size_t)(cb + r) * D_DIM + k0 + cq0);
                }
            }
            #pragma unroll
            for (int k = 0; k < BKk; ++k) {
                float a[8], b[8];
                *(float4*)&a[0] = *(const float4*)&As[cur][k][ty * 8];
                *(float4*)&a[4] = *(const float4*)&As[cur][k][ty * 8 + 4];
                const int pb0 = pcol(tx * 8);
                *(float4*)&b[0] = *(const float4*)&Bs[cur][k][pb0];
                *(float4*)&b[4] = *(const float4*)&Bs[cur][k][pb0 + 4];
                #pragma unroll
                for (int i = 0; i < 8; ++i)
                    #pragma unroll
                    for (int j = 0; j < 8; ++j)
                        acc[i][j] = fmaf(a[i], b[j], acc[i][j]);
            }
            __syncthreads();
            if (kt + 1 < NKT) {
                const int nb = cur ^ 1;
                #pragma unroll
                for (int it = 0; it < 2; ++it) {
                    int r = r0 + it * 64;
                    As[nb][cq0 + 0][r] = pa[it].x; As[nb][cq0 + 1][r] = pa[it].y;
                    As[nb][cq0 + 2][r] = pa[it].z; As[nb][cq0 + 3][r] = pa[it].w;
                    int pr = pcol(r);
                    Bs[nb][cq0 + 0][pr] = pb[it].x; Bs[nb][cq0 + 1][pr] = pb[it].y;
                    Bs[nb][cq0 + 2][pr] = pb[it].z; Bs[nb][cq0 + 3][pr] = pb[it].w;
                }
                __syncthreads();
            }
        }
        float e2v[8];
        #pragma unroll
        for (int j = 0; j < 8; ++j) e2v[j] = e2[cb + tx * 8 + j];
        #pragma unroll
        for (int i = 0; i < 8; ++i) {
            #pragma unroll
            for (int j = 0; j < 8; ++j) {
                float d = (x2r[i] - 2.0f * acc[i][j]) + e2v[j];
                int c = cb + tx * 8 + j;
                if (d < best[i]) { best[i] = d; bidx[i] = c; }
            }
        }
    }
    #pragma unroll
    for (int i = 0; i < 8; ++i) {
        float v = best[i]; int idx = bidx[i];
        #pragma unroll
        for (int off = 8; off >= 1; off >>= 1) {
            float ov = __shfl_xor(v, off, 64);
            int   oi = __shfl_xor(idx, off, 64);
            if (ov < v || (ov == v && oi < idx)) { v = ov; idx = oi; }
        }
        if (tx == 0) {
            int row = m0 + ty * 8 + i;
            bestv[ch * M_TOT + row] = v;
            besti[ch * M_TOT + row] = idx;
        }
    }
}

extern "C" void kernel_launch(void* const* d_in, const int* in_sizes, int n_in,
                              void* d_out, int out_size, void* d_ws, size_t ws_size,
                              hipStream_t stream) {
    const float* x = (const float*)d_in[0];   // [16384, 256]
    const float* e = (const float*)d_in[1];   // [8192, 256]
    float* out = (float*)d_out;

    float* wsf   = (float*)d_ws;
    float* x2    = wsf + WS_X2;
    float* e2    = wsf + WS_E2;
    float* bestv = wsf + WS_BV;
    int*   besti = (int*)(wsf + WS_BI);

    if (ws_size >= WS_NEED) {
        f16* sp = (f16*)(wsf + WS_SPL);
        split_kernel<<<(M_TOT + C_TOT) / 4, 256, 0, stream>>>(x, e, sp, x2, e2);
        mdist_kernel<<<(M_TOT / 256) * NCH, 512, 0, stream>>>(sp, x2, e2, bestv, besti);
        finalize_kernel<<<M_TOT / 4, 256, 0, stream>>>(e, bestv, besti, out, NPART);
    } else {
        sq_kernel<<<(M_TOT + C_TOT) / 4, 256, 0, stream>>>(x, e, x2, e2);
        dist_kernel<<<(M_TOT / BMm) * NCH, 256, 0, stream>>>(x, e, x2, e2, bestv, besti);
        finalize_kernel<<<M_TOT / 4, 256, 0, stream>>>(e, bestv, besti, out, NCH);
    }
}